// Round 11
// baseline (99.994 us; speedup 1.0000x reference)
//
#include <hip/hip_runtime.h>
#include <hip/hip_bf16.h>

#define NVOX 100000
#define CIN 32
#define COUT 32
#define KOFF 27
#define NTILE 6250            // NVOX / 16 exactly
#define KDEPTH 13             // gather prefetch depth

typedef __attribute__((ext_vector_type(8))) short short8;
typedef __attribute__((ext_vector_type(4))) float float4v;
typedef __attribute__((ext_vector_type(4))) int   int4v;

// fp32 -> bf16 round-to-nearest-even (finite inputs)
__device__ __forceinline__ short f2bf(float x) {
    union { float f; unsigned u; } v; v.f = x;
    unsigned u = v.u;
    u += 0x7FFFu + ((u >> 16) & 1u);
    return (short)(u >> 16);
}

#define FEAT_BLOCKS 3126      // ceil((NVOX+1)*CIN/4 / 256)

// ---- fused pre-pass: features fp32->bf16 (+zero row) AND weight B-fragments ----
__global__ __launch_bounds__(256) void cvt_kernel(
    const float* __restrict__ feat, const float* __restrict__ weight,
    unsigned short* __restrict__ fbf, short8* __restrict__ wfrag)
{
    if (blockIdx.x < FEAT_BLOCKS) {
        int i = (blockIdx.x * 256 + threadIdx.x) * 4;
        if (i < NVOX * CIN) {
            float4v f = *(const float4v*)(feat + i);
            short s[4] = { f2bf(f.x), f2bf(f.y), f2bf(f.z), f2bf(f.w) };
            *(ulonglong1*)(fbf + i) = *(ulonglong1*)s;
        } else if (i < (NVOX + 1) * CIN) {
            short s[4] = { 0, 0, 0, 0 };           // zero row for masked gathers
            *(ulonglong1*)(fbf + i) = *(ulonglong1*)s;
        }
    } else {
        // wfrag[k*128 + t*64 + ln][j] = W[k][ci=(ln>>4)*8+j][co=t*16+(ln&15)]
        int g = (blockIdx.x - FEAT_BLOCKS) * 256 + threadIdx.x;
        if (g >= KOFF * 2 * 64) return;
        int k   = g >> 7;
        int rem = g & 127;
        int t   = rem >> 6;
        int ln  = rem & 63;
        int co  = t * 16 + (ln & 15);
        int cib = (ln >> 4) * 8;
        const float* wp = weight + (k * CIN + cib) * COUT + co;
        short8 b;
#pragma unroll
        for (int j = 0; j < 8; ++j) b[j] = f2bf(wp[j * COUT]);
        wfrag[g] = b;
    }
}

__global__ __launch_bounds__(512, 4) void subm_conv_kernel(
    const unsigned short* __restrict__ fbf,   // bf16 features [N+1,32] (ws)
    const short8* __restrict__ wfrag,         // bf16 B-fragments (ws)
    const float* __restrict__ bias,           // fp32 [32]
    const int* __restrict__ nbr_idx,          // int32 [N,27]
    const int* __restrict__ nbr_mask,         // bool -> int32 [N,27]
    float* __restrict__ out)                  // fp32 [N,32]
{
    // 55,296 B buffer, 3 phases: metadata strips -> B-fragments -> store transpose
    __shared__ short8 wlds[KOFF * 2 * 64];

    const int tid  = threadIdx.x;
    const int lane = tid & 63;
    const int wave = tid >> 6;                 // 0..7
    const int m    = lane & 15;
    const int quad = lane >> 4;
    const int tile = blockIdx.x * 8 + wave;    // 16 voxels per wave
    const bool tv  = tile < NTILE;

    // ---- phase 1: coalesced metadata (108 int4 idx + 108 int4 mask per tile) ----
    const int base4 = tile * 108;
    const int p4a = lane, p4b = lane + 64;
    int4v id0{}, mk0{}, id1{}, mk1{};
    if (tv) {
        id0 = ((const int4v*)nbr_idx)[base4 + p4a];
        mk0 = ((const int4v*)nbr_mask)[base4 + p4a];
        if (p4b < 108) {
            id1 = ((const int4v*)nbr_idx)[base4 + p4b];
            mk1 = ((const int4v*)nbr_mask)[base4 + p4b];
        }
    }

    int* strip = (int*)wlds + wave * 432;      // wave-private
    {
        int4v e0;
        e0.x = (mk0.x ? id0.x : NVOX) << 6;
        e0.y = (mk0.y ? id0.y : NVOX) << 6;
        e0.z = (mk0.z ? id0.z : NVOX) << 6;
        e0.w = (mk0.w ? id0.w : NVOX) << 6;
        ((int4v*)strip)[p4a] = e0;
        if (p4b < 108) {
            int4v e1;
            e1.x = (mk1.x ? id1.x : NVOX) << 6;
            e1.y = (mk1.y ? id1.y : NVOX) << 6;
            e1.z = (mk1.z ? id1.z : NVOX) << 6;
            e1.w = (mk1.w ? id1.w : NVOX) << 6;
            ((int4v*)strip)[p4b] = e1;
        }
    }
    __syncthreads();                           // order LDS writes -> cross-lane reads

    // per-lane byte offsets: strip[m*27+k]; conflict-free (27 coprime 32), quad-broadcast
    int enc[KOFF];
#pragma unroll
    for (int k = 0; k < KOFF; ++k) enc[k] = strip[m * KOFF + k];
    __syncthreads();                           // all reads done before weight overwrite

    // ---- phase 2: stage weights ----
    for (int g = tid; g < KOFF * 2 * 64; g += 512) wlds[g] = wfrag[g];
    __syncthreads();

    float4v acc0 = {0.f, 0.f, 0.f, 0.f};
    float4v acc1 = {0.f, 0.f, 0.f, 0.f};

    const char* fb   = (const char*)fbf;
    const int   boff = quad * 16;              // byte offset of A-frag in row
    // invalid tiles: enc holds garbage-free zeros? strip was written with tv-guarded
    // loads zero-initialized -> enc = (0?0:..)<<6 ... ensure safety: force zero-row
    if (!tv) {
#pragma unroll
        for (int k = 0; k < KOFF; ++k) enc[k] = NVOX << 6;
    }

    // ---- depth-13 rotating gather pipeline, fully unrolled ----
    short8 abuf[KDEPTH];
#pragma unroll
    for (int k = 0; k < KDEPTH; ++k)
        abuf[k] = *(const short8*)(fb + (size_t)(unsigned)enc[k] + boff);

#pragma unroll
    for (int k = 0; k < KOFF; ++k) {
        const int slot = k % KDEPTH;
        short8 a = abuf[slot];
        if (k + KDEPTH < KOFF)
            abuf[slot] = *(const short8*)(fb + (size_t)(unsigned)enc[k + KDEPTH] + boff);

        short8 wb0 = wlds[k * 128 + lane];
        short8 wb1 = wlds[k * 128 + 64 + lane];
        acc0 = __builtin_amdgcn_mfma_f32_16x16x32_bf16(a, wb0, acc0, 0, 0, 0);
        acc1 = __builtin_amdgcn_mfma_f32_16x16x32_bf16(a, wb1, acc1, 0, 0, 0);
    }

    // ---- phase 3: coalesced epilogue via LDS transpose ----
    __syncthreads();                           // wlds reads done; safe to reuse
    float* tb = (float*)wlds + wave * (16 * 36);

    const float bs0 = bias[m];
    const float bs1 = bias[16 + m];
    const int v0 = tile * 16;
    if (tv) {
        // C/D layout: col (cout) = lane&15, row (voxel) = quad*4 + reg
#pragma unroll
        for (int r = 0; r < 4; ++r) {
            tb[(quad * 4 + r) * 36 + m]      = acc0[r] + bs0;
            tb[(quad * 4 + r) * 36 + 16 + m] = acc1[r] + bs1;
        }
#pragma unroll
        for (int p = 0; p < 2; ++p) {
            int flat = p * 64 + lane;
            int row  = flat >> 3;
            int ch   = flat & 7;
            float4v val = *(const float4v*)(tb + row * 36 + ch * 4);
            *(float4v*)(out + (size_t)(v0 + row) * COUT + ch * 4) = val;
        }
    }
}

extern "C" void kernel_launch(void* const* d_in, const int* in_sizes, int n_in,
                              void* d_out, int out_size, void* d_ws, size_t ws_size,
                              hipStream_t stream) {
    const float* feat = (const float*)d_in[0];
    const float* wgt  = (const float*)d_in[1];
    const float* bias = (const float*)d_in[2];
    const int*   nidx = (const int*)d_in[3];
    const int*   nmsk = (const int*)d_in[4];
    float*       out  = (float*)d_out;

    char* ws = (char*)d_ws;
    unsigned short* fbf   = (unsigned short*)ws;                 // 6,400,064 B
    short8*         wfrag = (short8*)(ws + 6400128);             //    55,296 B

    const int wgt_blocks = (KOFF * 2 * 64 + 255) / 256;          // 14
    cvt_kernel<<<FEAT_BLOCKS + wgt_blocks, 256, 0, stream>>>(feat, wgt, fbf, wfrag);

    const int block = 512;                         // 8 waves = 8 tiles = 128 voxels
    const int grid  = (NTILE + 7) / 8;             // 782
    subm_conv_kernel<<<grid, block, 0, stream>>>(fbf, wfrag, bias, nidx, nmsk, out);
}